// Round 13
// baseline (1431.835 us; speedup 1.0000x reference)
//
#include <hip/hip_runtime.h>
#include <hip/hip_fp16.h>

// ---------------------------------------------------------------------------
// GCN 3-layer forward.
// agg[i] = dinv[i] * ( sum_e h'[src_e] + h'[i] ),  h' = dinv*h folded into
// the GEMM epilogue; CSR = 2-byte src id, grouped by dst.
// CSR build = wave-aggregated binning (k_binA: ballot-compacted appends into
// 64 padded sub-regions, degree count folded in) + per-range compact scatter
// (k_fillB: working set fits one XCD L2, no polluting stream -> writes combine).
//
// d_ws (4-byte units):
//   csr  [E/2]       ushort src ids, grouped by dst
//   tmp  [64*cap]    packed uint (cLocal<<16 | src), 64 padded sub-regions
//   Ah   [N*64]      post-GEMM h' as f16
//   B    [N*128]     layer output f32
//   Ch   [N*8]       layer-3 post-GEMM h' as f16
//   dinv [N]
//   offs [N+1]
//   cnt  [N]
//   cur  [N]         fill cursor (init = offs)
//   bsum [256]
//   gcur [64]        sub-region append cursors (init = region base)
// ---------------------------------------------------------------------------

static inline int cdiv(int a, int b) { return (a + b - 1) / b; }

// zero cnt; init the 64 sub-region cursors
__global__ __launch_bounds__(256) void k_zero_init(int* cnt, int n, int* gcur, int cap) {
    int i = blockIdx.x * 256 + threadIdx.x;
    if (i < n) cnt[i] = 0;
    if (i < 64) gcur[i] = i * cap;
}

// Phase A: wave-aggregated binning into 8 dst ranges (+ degree count).
// Sub-counter set = blockIdx&7 -> 64 independent cursors, no hot atomics.
__global__ __launch_bounds__(256) void k_binA(const int* __restrict__ row, const int* __restrict__ col,
                                              int* cnt, int* gcur, unsigned int* __restrict__ tmp,
                                              int e, int rs, int nblk) {
    int sc = blockIdx.x & 7;
    int lane = threadIdx.x & 63;
    int stride = nblk * 256;
    for (int base_i = blockIdx.x * 256; base_i < e; base_i += stride) {
        int i = base_i + threadIdx.x;
        bool valid = i < e;
        int c = 0, r = 0, g = -1;
        if (valid) {
            c = col[i];
            r = row[i];
            atomicAdd(&cnt[c], 1);
            g = c / rs;
        }
        #pragma unroll
        for (int g8 = 0; g8 < 8; ++g8) {
            unsigned long long m = __ballot(valid && (g == g8));
            if (m == 0ull) continue;                      // uniform across wave
            int n8 = __popcll(m);
            int leader = __ffsll((unsigned long long)m) - 1;
            int base = 0;
            if (lane == leader) base = atomicAdd(&gcur[g8 * 8 + sc], n8);
            base = __shfl(base, leader);
            if (valid && (g == g8)) {
                int rank = __popcll(m & ((1ull << lane) - 1ull));
                tmp[base + rank] = ((unsigned int)(c - g8 * rs) << 16) | (unsigned int)r;
            }
        }
    }
}

// per-256-chunk sums for scan; also computes dinv = rsqrt(deg+1)
__global__ __launch_bounds__(256) void k_scanA(const int* __restrict__ cnt, int* bsum,
                                               float* __restrict__ dinv, int n) {
    __shared__ int s[256];
    int t = threadIdx.x;
    int i = blockIdx.x * 256 + t;
    int v = (i < n) ? cnt[i] : 0;
    if (i < n) dinv[i] = rsqrtf((float)(v + 1));
    s[t] = v;
    __syncthreads();
    for (int off = 128; off > 0; off >>= 1) {
        if (t < off) s[t] += s[t + off];
        __syncthreads();
    }
    if (t == 0) bsum[blockIdx.x] = s[0];
}

__global__ __launch_bounds__(256) void k_scanB(int* bsum, int nb) {
    __shared__ int s[256];
    int t = threadIdx.x;
    int v = (t < nb) ? bsum[t] : 0;
    s[t] = v;
    for (int off = 1; off < 256; off <<= 1) {
        __syncthreads();
        int x = (t >= off) ? s[t - off] : 0;
        __syncthreads();
        s[t] += x;
    }
    __syncthreads();
    if (t < nb) bsum[t] = s[t] - v;
}

// per-chunk exclusive scan + block offset -> offs; cursor copy for fill
__global__ __launch_bounds__(256) void k_scanC(const int* __restrict__ cnt, const int* __restrict__ bsum,
                                               int* offs, int* cur, int n) {
    __shared__ int s[256];
    int t = threadIdx.x;
    int i = blockIdx.x * 256 + t;
    int v = (i < n) ? cnt[i] : 0;
    s[t] = v;
    for (int off = 1; off < 256; off <<= 1) {
        __syncthreads();
        int x = (t >= off) ? s[t - off] : 0;
        __syncthreads();
        s[t] += x;
    }
    __syncthreads();
    int ov = bsum[blockIdx.x] + s[t] - v;
    if (i <= n) offs[i] = ov;
    if (i < n) cur[i] = ov;
}

// Phase B: per-range compact scatter. g = blockIdx&7 (XCD pin). Reads the
// range's 8 compact sub-regions, scatters 2B ids into its L2-resident slice.
__global__ __launch_bounds__(256) void k_fillB(const unsigned int* __restrict__ tmp,
                                               const int* __restrict__ gcur, int* cur,
                                               unsigned short* __restrict__ csr,
                                               int rs, int cap, int nblk) {
    int g = blockIdx.x & 7;
    int b = blockIdx.x >> 3;
    int base_c = g * rs;
    int stride = nblk * 256;
    for (int s = 0; s < 8; ++s) {
        int rid = g * 8 + s;
        int rbase = rid * cap;
        int rend = gcur[rid];
        for (int i = rbase + b * 256 + threadIdx.x; i < rend; i += stride) {
            unsigned int u = tmp[i];
            int c = base_c + (int)(u >> 16);
            int pos = atomicAdd(&cur[c], 1);
            csr[pos] = (unsigned short)(u & 0xffffu);
        }
    }
}

// Ah[n,128](f16) = dinv[row] * (X[n,128](f32) @ W[128,128]).
__global__ __launch_bounds__(256) void k_gemm128(const float* __restrict__ X, const float* __restrict__ W,
                                                 const float* __restrict__ dinv,
                                                 __half* __restrict__ Ah, int n) {
    __shared__ float sW[128 * 128];
    __shared__ float sX[16][128];
    int tid = threadIdx.x;
    for (int i = tid; i < 4096; i += 256)
        ((float4*)sW)[i] = ((const float4*)W)[i];

    int row0 = blockIdx.x * 128;
    int tx = tid & 15, ty = tid >> 4;
    float acc[8][8];
    #pragma unroll
    for (int i = 0; i < 8; ++i)
        #pragma unroll
        for (int j = 0; j < 8; ++j) acc[i][j] = 0.f;

    for (int k0 = 0; k0 < 128; k0 += 16) {
        __syncthreads();
        #pragma unroll
        for (int i = tid; i < 512; i += 256) {
            int r = i >> 2, kq = i & 3;
            int gr = row0 + r;
            float4 v = (gr < n) ? ((const float4*)X)[(size_t)gr * 32 + (k0 >> 2) + kq]
                                : make_float4(0.f, 0.f, 0.f, 0.f);
            sX[kq * 4 + 0][r] = v.x;
            sX[kq * 4 + 1][r] = v.y;
            sX[kq * 4 + 2][r] = v.z;
            sX[kq * 4 + 3][r] = v.w;
        }
        __syncthreads();
        #pragma unroll
        for (int kk = 0; kk < 16; ++kk) {
            float a[8], b[8];
            *(float4*)&a[0] = *(const float4*)&sX[kk][ty * 8];
            *(float4*)&a[4] = *(const float4*)&sX[kk][ty * 8 + 4];
            *(float4*)&b[0] = *(const float4*)&sW[(k0 + kk) * 128 + tx * 8];
            *(float4*)&b[4] = *(const float4*)&sW[(k0 + kk) * 128 + tx * 8 + 4];
            #pragma unroll
            for (int i = 0; i < 8; ++i)
                #pragma unroll
                for (int j = 0; j < 8; ++j)
                    acc[i][j] = fmaf(a[i], b[j], acc[i][j]);
        }
    }
    #pragma unroll
    for (int i = 0; i < 8; ++i) {
        int gr = row0 + ty * 8 + i;
        if (gr < n) {
            float di = dinv[gr];
            union { uint4 u; __half2 h[4]; } pk;
            pk.h[0] = __floats2half2_rn(di * acc[i][0], di * acc[i][1]);
            pk.h[1] = __floats2half2_rn(di * acc[i][2], di * acc[i][3]);
            pk.h[2] = __floats2half2_rn(di * acc[i][4], di * acc[i][5]);
            pk.h[3] = __floats2half2_rn(di * acc[i][6], di * acc[i][7]);
            ((uint4*)Ah)[(size_t)gr * 16 + tx] = pk.u;   // cols tx*8..+7
        }
    }
}

// Ch[n,16](f16) = dinv[row] * (X[n,128](f32) @ W[128,16]).
__global__ __launch_bounds__(256) void k_gemm16(const float* __restrict__ X, const float* __restrict__ W,
                                                const float* __restrict__ dinv,
                                                __half* __restrict__ Ch, int n) {
    __shared__ float sX[16 * 132];
    __shared__ float sW[128 * 16];
    int tid = threadIdx.x;
    for (int i = tid; i < 512; i += 256)
        ((float4*)sW)[i] = ((const float4*)W)[i];
    int row0 = blockIdx.x * 16;
    for (int i = tid; i < 512; i += 256) {
        int r = i >> 5, c = i & 31;
        int gr = row0 + r;
        float4 v = (gr < n) ? ((const float4*)X)[(size_t)gr * 32 + c]
                            : make_float4(0.f, 0.f, 0.f, 0.f);
        *(float4*)&sX[r * 132 + c * 4] = v;
    }
    __syncthreads();

    int rl = tid >> 4, cj = tid & 15;
    float acc = 0.f;
    #pragma unroll 8
    for (int k = 0; k < 128; ++k)
        acc = fmaf(sX[rl * 132 + k], sW[k * 16 + cj], acc);
    int gr = row0 + rl;
    if (gr < n) Ch[(size_t)gr * 16 + cj] = __float2half_rn(dinv[gr] * acc);
}

// F=128 gather-aggregate from f16 h': wave per node, 4 halves (8B)/lane,
// even/odd edge halves, 4-way unroll (8 edges in flight).
// out[i] = relu( dinv[i] * (sum_e h'[src_e] + h'[i]) + b )
__global__ __launch_bounds__(256) void k_agg128(const __half* __restrict__ Hh, const unsigned short* __restrict__ csr,
                                                const int* __restrict__ offs, const float* __restrict__ dinv,
                                                const float* __restrict__ b, float* __restrict__ out, int n) {
    int node = (blockIdx.x * 256 + threadIdx.x) >> 6;
    if (node >= n) return;
    int lane = threadIdx.x & 63;
    int sub  = lane & 31;     // uint2 (4 halves) within the 128-f row
    int half = lane >> 5;     // 0: even edges, 1: odd edges
    const uint2* H2 = (const uint2*)Hh;   // row stride = 32 uint2
    int ed = offs[node], end = offs[node + 1];
    float4 acc = make_float4(0.f, 0.f, 0.f, 0.f);

    #define EDGE_ADD(R)                                                          \
        {                                                                        \
            uint2 q = H2[(size_t)(R) * 32 + sub];                                \
            float2 f01 = __half22float2(*(const __half2*)&q.x);                  \
            float2 f23 = __half22float2(*(const __half2*)&q.y);                  \
            acc.x += f01.x; acc.y += f01.y;                                      \
            acc.z += f23.x; acc.w += f23.y;                                      \
        }

    for (; ed + 7 < end; ed += 8) {
        int r0 = csr[ed     + half];
        int r1 = csr[ed + 2 + half];
        int r2 = csr[ed + 4 + half];
        int r3 = csr[ed + 6 + half];
        EDGE_ADD(r0); EDGE_ADD(r1); EDGE_ADD(r2); EDGE_ADD(r3);
    }
    #pragma unroll
    for (int s = 0; s < 4; ++s) {          // tail: up to 7 edges
        int idx = ed + 2 * s + half;
        if (idx < end) {
            int r = csr[idx];
            EDGE_ADD(r);
        }
    }
    #undef EDGE_ADD

    acc.x += __shfl_xor(acc.x, 32);
    acc.y += __shfl_xor(acc.y, 32);
    acc.z += __shfl_xor(acc.z, 32);
    acc.w += __shfl_xor(acc.w, 32);

    float di = dinv[node];
    uint2 qh = H2[(size_t)node * 32 + sub];
    float2 h01 = __half22float2(*(const __half2*)&qh.x);
    float2 h23 = __half22float2(*(const __half2*)&qh.y);
    float4 bv = ((const float4*)b)[sub];
    float4 o;
    o.x = fmaxf(fmaf(di, acc.x + h01.x, bv.x), 0.f);
    o.y = fmaxf(fmaf(di, acc.y + h01.y, bv.y), 0.f);
    o.z = fmaxf(fmaf(di, acc.z + h23.x, bv.z), 0.f);
    o.w = fmaxf(fmaf(di, acc.w + h23.y, bv.w), 0.f);
    if (half == 0)
        ((float4*)out)[(size_t)node * 32 + sub] = o;
}

// F=16 gather-aggregate from f16 h': 8 lanes/node (4 x uint2, even/odd halves).
__global__ __launch_bounds__(256) void k_agg16(const __half* __restrict__ Ch, const unsigned short* __restrict__ csr,
                                               const int* __restrict__ offs, const float* __restrict__ dinv,
                                               const float* __restrict__ b, float* __restrict__ out, int n) {
    int t = blockIdx.x * 256 + threadIdx.x;
    int node = t >> 3;
    if (node >= n) return;
    int lane = t & 7;
    int sub  = lane & 3;      // uint2 (4 halves) within the 16-f row
    int half = lane >> 2;
    const uint2* C2 = (const uint2*)Ch;   // row stride = 4 uint2
    int ed = offs[node], end = offs[node + 1];
    float4 acc = make_float4(0.f, 0.f, 0.f, 0.f);

    #define EDGE_ADD16(R)                                                        \
        {                                                                        \
            uint2 q = C2[(size_t)(R) * 4 + sub];                                 \
            float2 f01 = __half22float2(*(const __half2*)&q.x);                  \
            float2 f23 = __half22float2(*(const __half2*)&q.y);                  \
            acc.x += f01.x; acc.y += f01.y;                                      \
            acc.z += f23.x; acc.w += f23.y;                                      \
        }

    for (; ed + 3 < end; ed += 4) {
        int r0 = csr[ed     + half];
        int r1 = csr[ed + 2 + half];
        EDGE_ADD16(r0); EDGE_ADD16(r1);
    }
    #pragma unroll
    for (int s = 0; s < 2; ++s) {          // tail: up to 3 edges
        int idx = ed + 2 * s + half;
        if (idx < end) {
            int r = csr[idx];
            EDGE_ADD16(r);
        }
    }
    #undef EDGE_ADD16

    acc.x += __shfl_xor(acc.x, 4);
    acc.y += __shfl_xor(acc.y, 4);
    acc.z += __shfl_xor(acc.z, 4);
    acc.w += __shfl_xor(acc.w, 4);

    float di = dinv[node];
    uint2 qh = C2[(size_t)node * 4 + sub];
    float2 h01 = __half22float2(*(const __half2*)&qh.x);
    float2 h23 = __half22float2(*(const __half2*)&qh.y);
    float4 bv = ((const float4*)b)[sub];
    float4 o;
    o.x = fmaxf(fmaf(di, acc.x + h01.x, bv.x), 0.f);
    o.y = fmaxf(fmaf(di, acc.y + h01.y, bv.y), 0.f);
    o.z = fmaxf(fmaf(di, acc.z + h23.x, bv.z), 0.f);
    o.w = fmaxf(fmaf(di, acc.w + h23.y, bv.w), 0.f);
    if (half == 0)
        ((float4*)out)[(size_t)node * 4 + sub] = o;
}

extern "C" void kernel_launch(void* const* d_in, const int* in_sizes, int n_in,
                              void* d_out, int out_size, void* d_ws, size_t ws_size,
                              hipStream_t stream) {
    const float* x  = (const float*)d_in[0];
    const int*   ei = (const int*)d_in[1];
    const float* W1 = (const float*)d_in[2];
    const float* b1 = (const float*)d_in[3];
    const float* W2 = (const float*)d_in[4];
    const float* b2 = (const float*)d_in[5];
    const float* W3 = (const float*)d_in[6];
    const float* b3 = (const float*)d_in[7];

    const int n = in_sizes[0] / 128;   // 50000 (< 65536, required by 16-bit ids)
    const int e = in_sizes[1] / 2;
    const int* row = ei;       // source j
    const int* col = ei + e;   // target i
    const int rs  = (n + 7) >> 3;
    const int cap = e / 64 + 8192;     // padded sub-region capacity

    unsigned short* csr = (unsigned short*)d_ws;
    unsigned int*   tmp = (unsigned int*)(csr + ((e + 1) & ~1));
    __half* Ah  = (__half*)(tmp + (size_t)64 * cap);
    float*  B   = (float*)(Ah + (size_t)n * 128);
    __half* Ch  = (__half*)(B + (size_t)n * 128);
    float* dinv = (float*)(Ch + (size_t)n * 16);
    int*   offs = (int*)(dinv + n);
    int*   cnt  = offs + (n + 1);
    int*   cur  = cnt + n;
    int*   bsum = cur + n;
    int*   gcur = bsum + 256;
    float* out  = (float*)d_out;

    const int nb = cdiv(n + 1, 256);
    const int binBlocks   = 1024;
    const int fillBBlocks = 128;       // per range; grid = 8*128

    // --- CSR build ---
    k_zero_init<<<cdiv(n, 256), 256, 0, stream>>>(cnt, n, gcur, cap);
    k_binA     <<<binBlocks, 256, 0, stream>>>(row, col, cnt, gcur, tmp, e, rs, binBlocks);
    k_scanA    <<<nb, 256, 0, stream>>>(cnt, bsum, dinv, n);
    k_scanB    <<<1, 256, 0, stream>>>(bsum, nb);
    k_scanC    <<<nb, 256, 0, stream>>>(cnt, bsum, offs, cur, n);
    k_fillB    <<<8 * fillBBlocks, 256, 0, stream>>>(tmp, gcur, cur, csr, rs, cap, fillBBlocks);

    // --- layer 1 ---
    k_gemm128<<<cdiv(n, 128), 256, 0, stream>>>(x, W1, dinv, Ah, n);
    k_agg128 <<<cdiv(n * 64, 256), 256, 0, stream>>>(Ah, csr, offs, dinv, b1, B, n);
    // --- layer 2 ---
    k_gemm128<<<cdiv(n, 128), 256, 0, stream>>>(B, W2, dinv, Ah, n);
    k_agg128 <<<cdiv(n * 64, 256), 256, 0, stream>>>(Ah, csr, offs, dinv, b2, B, n);
    // --- layer 3 ---
    k_gemm16 <<<cdiv(n, 16), 256, 0, stream>>>(B, W3, dinv, Ch, n);
    k_agg16  <<<cdiv(n * 8, 256), 256, 0, stream>>>(Ch, csr, offs, dinv, b3, out, n);
}

// Round 14
// 353.825 us; speedup vs baseline: 4.0467x; 4.0467x over previous
//
#include <hip/hip_runtime.h>
#include <hip/hip_fp16.h>

// ---------------------------------------------------------------------------
// GCN 3-layer forward.  (R12 structure + slim-LDS GEMM128.)
// agg[i] = dinv[i] * ( sum_e h'[src_e] + h'[i] ),  h' = dinv*h folded into
// the GEMM epilogue. CSR = 2-byte src id only (3.2 MB), grouped by dst.
// Fill is XCD-partitioned (8 dst ranges, blockIdx&7), plain loads.
// GEMM128 stages BOTH X and W in 16-k LDS slices (16 KB total) -> 8 blocks/CU.
//
// d_ws (4-byte units):
//   csr  [E/2]   ushort src ids, grouped by dst
//   Ah   [N*64]  post-GEMM h' as f16 (128 halves/row)
//   B    [N*128] layer output f32
//   Ch   [N*8]   layer-3 post-GEMM h' as f16
//   dinv [N]
//   offs [N+1]
//   cnt  [N]
//   cur  [N]     fill cursor (init = offs)
//   bsum [256]
// ---------------------------------------------------------------------------

static inline int cdiv(int a, int b) { return (a + b - 1) / b; }

__global__ __launch_bounds__(256) void k_zero_int(int* p, int n) {
    int i = blockIdx.x * 256 + threadIdx.x;
    if (i < n) p[i] = 0;
}

__global__ __launch_bounds__(256) void k_count(const int* __restrict__ col, int* cnt, int e) {
    int i = blockIdx.x * 256 + threadIdx.x;
    if (i < e) atomicAdd(&cnt[col[i]], 1);
}

// per-256-chunk sums for scan; also computes dinv = rsqrt(deg+1)
__global__ __launch_bounds__(256) void k_scanA(const int* __restrict__ cnt, int* bsum,
                                               float* __restrict__ dinv, int n) {
    __shared__ int s[256];
    int t = threadIdx.x;
    int i = blockIdx.x * 256 + t;
    int v = (i < n) ? cnt[i] : 0;
    if (i < n) dinv[i] = rsqrtf((float)(v + 1));
    s[t] = v;
    __syncthreads();
    for (int off = 128; off > 0; off >>= 1) {
        if (t < off) s[t] += s[t + off];
        __syncthreads();
    }
    if (t == 0) bsum[blockIdx.x] = s[0];
}

__global__ __launch_bounds__(256) void k_scanB(int* bsum, int nb) {
    __shared__ int s[256];
    int t = threadIdx.x;
    int v = (t < nb) ? bsum[t] : 0;
    s[t] = v;
    for (int off = 1; off < 256; off <<= 1) {
        __syncthreads();
        int x = (t >= off) ? s[t - off] : 0;
        __syncthreads();
        s[t] += x;
    }
    __syncthreads();
    if (t < nb) bsum[t] = s[t] - v;
}

// per-chunk exclusive scan + block offset -> offs; cursor copy for fill
__global__ __launch_bounds__(256) void k_scanC(const int* __restrict__ cnt, const int* __restrict__ bsum,
                                               int* offs, int* cur, int n) {
    __shared__ int s[256];
    int t = threadIdx.x;
    int i = blockIdx.x * 256 + t;
    int v = (i < n) ? cnt[i] : 0;
    s[t] = v;
    for (int off = 1; off < 256; off <<= 1) {
        __syncthreads();
        int x = (t >= off) ? s[t - off] : 0;
        __syncthreads();
        s[t] += x;
    }
    __syncthreads();
    int ov = bsum[blockIdx.x] + s[t] - v;
    if (i <= n) offs[i] = ov;
    if (i < n) cur[i] = ov;
}

// XCD-partitioned fill: range g = blockIdx&7 owns dst in [g*rs, g*rs+rs).
__global__ __launch_bounds__(256) void k_fill_xcd(const int* __restrict__ row, const int* __restrict__ col,
                                                  int* cur, unsigned short* __restrict__ csr,
                                                  int e, int n, int nblk) {
    int g = blockIdx.x & 7;
    int b = blockIdx.x >> 3;
    int rs = (n + 7) >> 3;
    int lo = g * rs;
    int hi = min(lo + rs, n);
    int stride = nblk * 256;
    for (int i = b * 256 + threadIdx.x; i < e; i += stride) {
        int c = col[i];
        if (c >= lo && c < hi) {
            int pos = atomicAdd(&cur[c], 1);
            csr[pos] = (unsigned short)row[i];
        }
    }
}

// Ah[n,128](f16) = dinv[row] * (X[n,128](f32) @ W[128,128]).
// 128-row tile, 8x8 micro-tile. X AND W staged in 16-k LDS slices (16 KB).
__global__ __launch_bounds__(256) void k_gemm128(const float* __restrict__ X, const float* __restrict__ W,
                                                 const float* __restrict__ dinv,
                                                 __half* __restrict__ Ah, int n) {
    __shared__ float sW[16][128];   // W[k0+kk][j]
    __shared__ float sX[16][128];   // X^T[k0+kk][r]
    int tid = threadIdx.x;

    int row0 = blockIdx.x * 128;
    int tx = tid & 15, ty = tid >> 4;
    float acc[8][8];
    #pragma unroll
    for (int i = 0; i < 8; ++i)
        #pragma unroll
        for (int j = 0; j < 8; ++j) acc[i][j] = 0.f;

    for (int k0 = 0; k0 < 128; k0 += 16) {
        __syncthreads();   // previous iteration's LDS reads complete
        // stage W[k0..+15][0..127]: 512 float4, 2 per thread (coalesced)
        #pragma unroll
        for (int i = tid; i < 512; i += 256) {
            int kk = i >> 5, c4 = i & 31;
            *(float4*)&sW[kk][c4 * 4] = ((const float4*)W)[(size_t)(k0 + kk) * 32 + c4];
        }
        // stage X[row0..+127][k0..+15] transposed: 512 float4, 2 per thread
        #pragma unroll
        for (int i = tid; i < 512; i += 256) {
            int r = i >> 2, kq = i & 3;
            int gr = row0 + r;
            float4 v = (gr < n) ? ((const float4*)X)[(size_t)gr * 32 + (k0 >> 2) + kq]
                                : make_float4(0.f, 0.f, 0.f, 0.f);
            sX[kq * 4 + 0][r] = v.x;
            sX[kq * 4 + 1][r] = v.y;
            sX[kq * 4 + 2][r] = v.z;
            sX[kq * 4 + 3][r] = v.w;
        }
        __syncthreads();
        #pragma unroll
        for (int kk = 0; kk < 16; ++kk) {
            float a[8], b[8];
            *(float4*)&a[0] = *(const float4*)&sX[kk][ty * 8];
            *(float4*)&a[4] = *(const float4*)&sX[kk][ty * 8 + 4];
            *(float4*)&b[0] = *(const float4*)&sW[kk][tx * 8];
            *(float4*)&b[4] = *(const float4*)&sW[kk][tx * 8 + 4];
            #pragma unroll
            for (int i = 0; i < 8; ++i)
                #pragma unroll
                for (int j = 0; j < 8; ++j)
                    acc[i][j] = fmaf(a[i], b[j], acc[i][j]);
        }
    }
    #pragma unroll
    for (int i = 0; i < 8; ++i) {
        int gr = row0 + ty * 8 + i;
        if (gr < n) {
            float di = dinv[gr];
            union { uint4 u; __half2 h[4]; } pk;
            pk.h[0] = __floats2half2_rn(di * acc[i][0], di * acc[i][1]);
            pk.h[1] = __floats2half2_rn(di * acc[i][2], di * acc[i][3]);
            pk.h[2] = __floats2half2_rn(di * acc[i][4], di * acc[i][5]);
            pk.h[3] = __floats2half2_rn(di * acc[i][6], di * acc[i][7]);
            ((uint4*)Ah)[(size_t)gr * 16 + tx] = pk.u;   // cols tx*8..+7
        }
    }
}

// Ch[n,16](f16) = dinv[row] * (X[n,128](f32) @ W[128,16]).
__global__ __launch_bounds__(256) void k_gemm16(const float* __restrict__ X, const float* __restrict__ W,
                                                const float* __restrict__ dinv,
                                                __half* __restrict__ Ch, int n) {
    __shared__ float sX[16 * 132];
    __shared__ float sW[128 * 16];
    int tid = threadIdx.x;
    for (int i = tid; i < 512; i += 256)
        ((float4*)sW)[i] = ((const float4*)W)[i];
    int row0 = blockIdx.x * 16;
    for (int i = tid; i < 512; i += 256) {
        int r = i >> 5, c = i & 31;
        int gr = row0 + r;
        float4 v = (gr < n) ? ((const float4*)X)[(size_t)gr * 32 + c]
                            : make_float4(0.f, 0.f, 0.f, 0.f);
        *(float4*)&sX[r * 132 + c * 4] = v;
    }
    __syncthreads();

    int rl = tid >> 4, cj = tid & 15;
    float acc = 0.f;
    #pragma unroll 8
    for (int k = 0; k < 128; ++k)
        acc = fmaf(sX[rl * 132 + k], sW[k * 16 + cj], acc);
    int gr = row0 + rl;
    if (gr < n) Ch[(size_t)gr * 16 + cj] = __float2half_rn(dinv[gr] * acc);
}

// F=128 gather-aggregate from f16 h': wave per node, 4 halves (8B)/lane,
// even/odd edge halves, 4-way unroll (8 edges in flight).
// out[i] = relu( dinv[i] * (sum_e h'[src_e] + h'[i]) + b )
__global__ __launch_bounds__(256) void k_agg128(const __half* __restrict__ Hh, const unsigned short* __restrict__ csr,
                                                const int* __restrict__ offs, const float* __restrict__ dinv,
                                                const float* __restrict__ b, float* __restrict__ out, int n) {
    int node = (blockIdx.x * 256 + threadIdx.x) >> 6;
    if (node >= n) return;
    int lane = threadIdx.x & 63;
    int sub  = lane & 31;     // uint2 (4 halves) within the 128-f row
    int half = lane >> 5;     // 0: even edges, 1: odd edges
    const uint2* H2 = (const uint2*)Hh;   // row stride = 32 uint2
    int ed = offs[node], end = offs[node + 1];
    float4 acc = make_float4(0.f, 0.f, 0.f, 0.f);

    #define EDGE_ADD(R)                                                          \
        {                                                                        \
            uint2 q = H2[(size_t)(R) * 32 + sub];                                \
            float2 f01 = __half22float2(*(const __half2*)&q.x);                  \
            float2 f23 = __half22float2(*(const __half2*)&q.y);                  \
            acc.x += f01.x; acc.y += f01.y;                                      \
            acc.z += f23.x; acc.w += f23.y;                                      \
        }

    for (; ed + 7 < end; ed += 8) {
        int r0 = csr[ed     + half];
        int r1 = csr[ed + 2 + half];
        int r2 = csr[ed + 4 + half];
        int r3 = csr[ed + 6 + half];
        EDGE_ADD(r0); EDGE_ADD(r1); EDGE_ADD(r2); EDGE_ADD(r3);
    }
    #pragma unroll
    for (int s = 0; s < 4; ++s) {          // tail: up to 7 edges
        int idx = ed + 2 * s + half;
        if (idx < end) {
            int r = csr[idx];
            EDGE_ADD(r);
        }
    }
    #undef EDGE_ADD

    acc.x += __shfl_xor(acc.x, 32);
    acc.y += __shfl_xor(acc.y, 32);
    acc.z += __shfl_xor(acc.z, 32);
    acc.w += __shfl_xor(acc.w, 32);

    float di = dinv[node];
    uint2 qh = H2[(size_t)node * 32 + sub];
    float2 h01 = __half22float2(*(const __half2*)&qh.x);
    float2 h23 = __half22float2(*(const __half2*)&qh.y);
    float4 bv = ((const float4*)b)[sub];
    float4 o;
    o.x = fmaxf(fmaf(di, acc.x + h01.x, bv.x), 0.f);
    o.y = fmaxf(fmaf(di, acc.y + h01.y, bv.y), 0.f);
    o.z = fmaxf(fmaf(di, acc.z + h23.x, bv.z), 0.f);
    o.w = fmaxf(fmaf(di, acc.w + h23.y, bv.w), 0.f);
    if (half == 0)
        ((float4*)out)[(size_t)node * 32 + sub] = o;
}

// F=16 gather-aggregate from f16 h': 8 lanes/node (4 x uint2, even/odd halves).
__global__ __launch_bounds__(256) void k_agg16(const __half* __restrict__ Ch, const unsigned short* __restrict__ csr,
                                               const int* __restrict__ offs, const float* __restrict__ dinv,
                                               const float* __restrict__ b, float* __restrict__ out, int n) {
    int t = blockIdx.x * 256 + threadIdx.x;
    int node = t >> 3;
    if (node >= n) return;
    int lane = t & 7;
    int sub  = lane & 3;      // uint2 (4 halves) within the 16-f row
    int half = lane >> 2;
    const uint2* C2 = (const uint2*)Ch;   // row stride = 4 uint2
    int ed = offs[node], end = offs[node + 1];
    float4 acc = make_float4(0.f, 0.f, 0.f, 0.f);

    #define EDGE_ADD16(R)                                                        \
        {                                                                        \
            uint2 q = C2[(size_t)(R) * 4 + sub];                                 \
            float2 f01 = __half22float2(*(const __half2*)&q.x);                  \
            float2 f23 = __half22float2(*(const __half2*)&q.y);                  \
            acc.x += f01.x; acc.y += f01.y;                                      \
            acc.z += f23.x; acc.w += f23.y;                                      \
        }

    for (; ed + 3 < end; ed += 4) {
        int r0 = csr[ed     + half];
        int r1 = csr[ed + 2 + half];
        EDGE_ADD16(r0); EDGE_ADD16(r1);
    }
    #pragma unroll
    for (int s = 0; s < 2; ++s) {          // tail: up to 3 edges
        int idx = ed + 2 * s + half;
        if (idx < end) {
            int r = csr[idx];
            EDGE_ADD16(r);
        }
    }
    #undef EDGE_ADD16

    acc.x += __shfl_xor(acc.x, 4);
    acc.y += __shfl_xor(acc.y, 4);
    acc.z += __shfl_xor(acc.z, 4);
    acc.w += __shfl_xor(acc.w, 4);

    float di = dinv[node];
    uint2 qh = C2[(size_t)node * 4 + sub];
    float2 h01 = __half22float2(*(const __half2*)&qh.x);
    float2 h23 = __half22float2(*(const __half2*)&qh.y);
    float4 bv = ((const float4*)b)[sub];
    float4 o;
    o.x = fmaxf(fmaf(di, acc.x + h01.x, bv.x), 0.f);
    o.y = fmaxf(fmaf(di, acc.y + h01.y, bv.y), 0.f);
    o.z = fmaxf(fmaf(di, acc.z + h23.x, bv.z), 0.f);
    o.w = fmaxf(fmaf(di, acc.w + h23.y, bv.w), 0.f);
    if (half == 0)
        ((float4*)out)[(size_t)node * 4 + sub] = o;
}

extern "C" void kernel_launch(void* const* d_in, const int* in_sizes, int n_in,
                              void* d_out, int out_size, void* d_ws, size_t ws_size,
                              hipStream_t stream) {
    const float* x  = (const float*)d_in[0];
    const int*   ei = (const int*)d_in[1];
    const float* W1 = (const float*)d_in[2];
    const float* b1 = (const float*)d_in[3];
    const float* W2 = (const float*)d_in[4];
    const float* b2 = (const float*)d_in[5];
    const float* W3 = (const float*)d_in[6];
    const float* b3 = (const float*)d_in[7];

    const int n = in_sizes[0] / 128;   // 50000 (< 65536, required by 16-bit CSR)
    const int e = in_sizes[1] / 2;
    const int* row = ei;       // source j
    const int* col = ei + e;   // target i

    unsigned short* csr = (unsigned short*)d_ws;
    __half* Ah  = (__half*)(csr + ((e + 1) & ~1));
    float*  B   = (float*)(Ah + (size_t)n * 128);
    __half* Ch  = (__half*)(B + (size_t)n * 128);
    float* dinv = (float*)(Ch + (size_t)n * 16);
    int*   offs = (int*)(dinv + n);
    int*   cnt  = offs + (n + 1);
    int*   cur  = cnt + n;
    int*   bsum = cur + n;
    float* out  = (float*)d_out;

    const int nb = cdiv(n + 1, 256);
    const int fillBlocks = 256;          // per replica; grid = 8 * 256

    // --- CSR build ---
    k_zero_int<<<cdiv(n, 256), 256, 0, stream>>>(cnt, n);
    k_count   <<<cdiv(e, 256), 256, 0, stream>>>(col, cnt, e);
    k_scanA   <<<nb, 256, 0, stream>>>(cnt, bsum, dinv, n);
    k_scanB   <<<1, 256, 0, stream>>>(bsum, nb);
    k_scanC   <<<nb, 256, 0, stream>>>(cnt, bsum, offs, cur, n);
    k_fill_xcd<<<8 * fillBlocks, 256, 0, stream>>>(row, col, cur, csr, e, n, fillBlocks);

    // --- layer 1 ---
    k_gemm128<<<cdiv(n, 128), 256, 0, stream>>>(x, W1, dinv, Ah, n);
    k_agg128 <<<cdiv(n * 64, 256), 256, 0, stream>>>(Ah, csr, offs, dinv, b1, B, n);
    // --- layer 2 ---
    k_gemm128<<<cdiv(n, 128), 256, 0, stream>>>(B, W2, dinv, Ah, n);
    k_agg128 <<<cdiv(n * 64, 256), 256, 0, stream>>>(Ah, csr, offs, dinv, b2, B, n);
    // --- layer 3 ---
    k_gemm16 <<<cdiv(n, 16), 256, 0, stream>>>(B, W3, dinv, Ch, n);
    k_agg16  <<<cdiv(n * 8, 256), 256, 0, stream>>>(Ch, csr, offs, dinv, b3, out, n);
}

// Round 15
// 348.621 us; speedup vs baseline: 4.1071x; 1.0149x over previous
//
#include <hip/hip_runtime.h>
#include <hip/hip_fp16.h>

// ---------------------------------------------------------------------------
// GCN 3-layer forward.  (R14 structure + vec count, merged scan, deep agg.)
// agg[i] = dinv[i] * ( sum_e h'[src_e] + h'[i] ),  h' = dinv*h folded into
// the GEMM epilogue. CSR = 2-byte src id only (3.2 MB), grouped by dst.
// Fill is XCD-partitioned (8 dst ranges, blockIdx&7), plain loads.
// GEMM128 stages X and W in 16-k LDS slices (16 KB) -> high occupancy.
//
// d_ws (4-byte units):
//   csr  [E/2]   ushort src ids, grouped by dst
//   Ah   [N*64]  post-GEMM h' as f16 (128 halves/row)
//   B    [N*128] layer output f32
//   Ch   [N*8]   layer-3 post-GEMM h' as f16
//   dinv [N]
//   offs [N+1]
//   cnt  [N]
//   cur  [N]     fill cursor (init = offs)
//   bsum [256]
// ---------------------------------------------------------------------------

static inline int cdiv(int a, int b) { return (a + b - 1) / b; }

__global__ __launch_bounds__(256) void k_zero_int(int* p, int n) {
    int i = blockIdx.x * 256 + threadIdx.x;
    if (i < n) p[i] = 0;
}

// vectorized degree count: int4 col reads, 4 atomics/lane/iter
__global__ __launch_bounds__(256) void k_count4(const int4* __restrict__ col4, int* cnt, int e4,
                                                const int* __restrict__ col, int e) {
    int i = blockIdx.x * 256 + threadIdx.x;
    if (i < e4) {
        int4 c = col4[i];
        atomicAdd(&cnt[c.x], 1);
        atomicAdd(&cnt[c.y], 1);
        atomicAdd(&cnt[c.z], 1);
        atomicAdd(&cnt[c.w], 1);
    }
    if (i == 0) {
        for (int k = e4 * 4; k < e; ++k) atomicAdd(&cnt[col[k]], 1);
    }
}

// per-256-chunk sums for scan; also computes dinv = rsqrt(deg+1)
__global__ __launch_bounds__(256) void k_scanA(const int* __restrict__ cnt, int* bsum,
                                               float* __restrict__ dinv, int n) {
    __shared__ int s[256];
    int t = threadIdx.x;
    int i = blockIdx.x * 256 + t;
    int v = (i < n) ? cnt[i] : 0;
    if (i < n) dinv[i] = rsqrtf((float)(v + 1));
    s[t] = v;
    __syncthreads();
    for (int off = 128; off > 0; off >>= 1) {
        if (t < off) s[t] += s[t + off];
        __syncthreads();
    }
    if (t == 0) bsum[blockIdx.x] = s[0];
}

// merged: per-block prefix of bsum (redundant, cheap) + per-chunk exclusive
// scan -> offs; cursor copy for fill. (Removes the separate scanB launch.)
__global__ __launch_bounds__(256) void k_scanC(const int* __restrict__ cnt, const int* __restrict__ bsum,
                                               int* offs, int* cur, int n) {
    __shared__ int s[256];
    int t = threadIdx.x;
    // prefix = sum of bsum[0..blockIdx)
    int p = 0;
    for (int j = t; j < (int)blockIdx.x; j += 256) p += bsum[j];
    s[t] = p;
    __syncthreads();
    for (int off = 128; off > 0; off >>= 1) {
        if (t < off) s[t] += s[t + off];
        __syncthreads();
    }
    int blockPrefix = s[0];
    __syncthreads();
    int i = blockIdx.x * 256 + t;
    int v = (i < n) ? cnt[i] : 0;
    s[t] = v;
    for (int off = 1; off < 256; off <<= 1) {
        __syncthreads();
        int x = (t >= off) ? s[t - off] : 0;
        __syncthreads();
        s[t] += x;
    }
    __syncthreads();
    int ov = blockPrefix + s[t] - v;
    if (i <= n) offs[i] = ov;
    if (i < n) cur[i] = ov;
}

// XCD-partitioned fill: range g = blockIdx&7 owns dst in [g*rs, g*rs+rs).
__global__ __launch_bounds__(256) void k_fill_xcd(const int* __restrict__ row, const int* __restrict__ col,
                                                  int* cur, unsigned short* __restrict__ csr,
                                                  int e, int n, int nblk) {
    int g = blockIdx.x & 7;
    int b = blockIdx.x >> 3;
    int rs = (n + 7) >> 3;
    int lo = g * rs;
    int hi = min(lo + rs, n);
    int stride = nblk * 256;
    for (int i = b * 256 + threadIdx.x; i < e; i += stride) {
        int c = col[i];
        if (c >= lo && c < hi) {
            int pos = atomicAdd(&cur[c], 1);
            csr[pos] = (unsigned short)row[i];
        }
    }
}

// Ah[n,128](f16) = dinv[row] * (X[n,128](f32) @ W[128,128]).
// 128-row tile, 8x8 micro-tile. X AND W staged in 16-k LDS slices (16 KB).
__global__ __launch_bounds__(256) void k_gemm128(const float* __restrict__ X, const float* __restrict__ W,
                                                 const float* __restrict__ dinv,
                                                 __half* __restrict__ Ah, int n) {
    __shared__ float sW[16][128];   // W[k0+kk][j]
    __shared__ float sX[16][128];   // X^T[k0+kk][r]
    int tid = threadIdx.x;

    int row0 = blockIdx.x * 128;
    int tx = tid & 15, ty = tid >> 4;
    float acc[8][8];
    #pragma unroll
    for (int i = 0; i < 8; ++i)
        #pragma unroll
        for (int j = 0; j < 8; ++j) acc[i][j] = 0.f;

    for (int k0 = 0; k0 < 128; k0 += 16) {
        __syncthreads();
        #pragma unroll
        for (int i = tid; i < 512; i += 256) {
            int kk = i >> 5, c4 = i & 31;
            *(float4*)&sW[kk][c4 * 4] = ((const float4*)W)[(size_t)(k0 + kk) * 32 + c4];
        }
        #pragma unroll
        for (int i = tid; i < 512; i += 256) {
            int r = i >> 2, kq = i & 3;
            int gr = row0 + r;
            float4 v = (gr < n) ? ((const float4*)X)[(size_t)gr * 32 + (k0 >> 2) + kq]
                                : make_float4(0.f, 0.f, 0.f, 0.f);
            sX[kq * 4 + 0][r] = v.x;
            sX[kq * 4 + 1][r] = v.y;
            sX[kq * 4 + 2][r] = v.z;
            sX[kq * 4 + 3][r] = v.w;
        }
        __syncthreads();
        #pragma unroll
        for (int kk = 0; kk < 16; ++kk) {
            float a[8], b[8];
            *(float4*)&a[0] = *(const float4*)&sX[kk][ty * 8];
            *(float4*)&a[4] = *(const float4*)&sX[kk][ty * 8 + 4];
            *(float4*)&b[0] = *(const float4*)&sW[kk][tx * 8];
            *(float4*)&b[4] = *(const float4*)&sW[kk][tx * 8 + 4];
            #pragma unroll
            for (int i = 0; i < 8; ++i)
                #pragma unroll
                for (int j = 0; j < 8; ++j)
                    acc[i][j] = fmaf(a[i], b[j], acc[i][j]);
        }
    }
    #pragma unroll
    for (int i = 0; i < 8; ++i) {
        int gr = row0 + ty * 8 + i;
        if (gr < n) {
            float di = dinv[gr];
            union { uint4 u; __half2 h[4]; } pk;
            pk.h[0] = __floats2half2_rn(di * acc[i][0], di * acc[i][1]);
            pk.h[1] = __floats2half2_rn(di * acc[i][2], di * acc[i][3]);
            pk.h[2] = __floats2half2_rn(di * acc[i][4], di * acc[i][5]);
            pk.h[3] = __floats2half2_rn(di * acc[i][6], di * acc[i][7]);
            ((uint4*)Ah)[(size_t)gr * 16 + tx] = pk.u;   // cols tx*8..+7
        }
    }
}

// Ch[n,16](f16) = dinv[row] * (X[n,128](f32) @ W[128,16]).
__global__ __launch_bounds__(256) void k_gemm16(const float* __restrict__ X, const float* __restrict__ W,
                                                const float* __restrict__ dinv,
                                                __half* __restrict__ Ch, int n) {
    __shared__ float sX[16 * 132];
    __shared__ float sW[128 * 16];
    int tid = threadIdx.x;
    for (int i = tid; i < 512; i += 256)
        ((float4*)sW)[i] = ((const float4*)W)[i];
    int row0 = blockIdx.x * 16;
    for (int i = tid; i < 512; i += 256) {
        int r = i >> 5, c = i & 31;
        int gr = row0 + r;
        float4 v = (gr < n) ? ((const float4*)X)[(size_t)gr * 32 + c]
                            : make_float4(0.f, 0.f, 0.f, 0.f);
        *(float4*)&sX[r * 132 + c * 4] = v;
    }
    __syncthreads();

    int rl = tid >> 4, cj = tid & 15;
    float acc = 0.f;
    #pragma unroll 8
    for (int k = 0; k < 128; ++k)
        acc = fmaf(sX[rl * 132 + k], sW[k * 16 + cj], acc);
    int gr = row0 + rl;
    if (gr < n) Ch[(size_t)gr * 16 + cj] = __float2half_rn(dinv[gr] * acc);
}

// F=128 gather-aggregate from f16 h': wave per node, 4 halves (8B)/lane,
// even/odd edge halves, 8-way unroll (16 edges in flight).
// out[i] = relu( dinv[i] * (sum_e h'[src_e] + h'[i]) + b )
__global__ __launch_bounds__(256) void k_agg128(const __half* __restrict__ Hh, const unsigned short* __restrict__ csr,
                                                const int* __restrict__ offs, const float* __restrict__ dinv,
                                                const float* __restrict__ b, float* __restrict__ out, int n) {
    int node = (blockIdx.x * 256 + threadIdx.x) >> 6;
    if (node >= n) return;
    int lane = threadIdx.x & 63;
    int sub  = lane & 31;     // uint2 (4 halves) within the 128-f row
    int half = lane >> 5;     // 0: even edges, 1: odd edges
    const uint2* H2 = (const uint2*)Hh;   // row stride = 32 uint2
    int ed = offs[node], end = offs[node + 1];
    float4 acc = make_float4(0.f, 0.f, 0.f, 0.f);

    #define EDGE_ADD(R)                                                          \
        {                                                                        \
            uint2 q = H2[(size_t)(R) * 32 + sub];                                \
            float2 f01 = __half22float2(*(const __half2*)&q.x);                  \
            float2 f23 = __half22float2(*(const __half2*)&q.y);                  \
            acc.x += f01.x; acc.y += f01.y;                                      \
            acc.z += f23.x; acc.w += f23.y;                                      \
        }

    for (; ed + 15 < end; ed += 16) {      // 16 edges in flight (8 per half)
        int r0 = csr[ed      + half];
        int r1 = csr[ed + 2  + half];
        int r2 = csr[ed + 4  + half];
        int r3 = csr[ed + 6  + half];
        int r4 = csr[ed + 8  + half];
        int r5 = csr[ed + 10 + half];
        int r6 = csr[ed + 12 + half];
        int r7 = csr[ed + 14 + half];
        EDGE_ADD(r0); EDGE_ADD(r1); EDGE_ADD(r2); EDGE_ADD(r3);
        EDGE_ADD(r4); EDGE_ADD(r5); EDGE_ADD(r6); EDGE_ADD(r7);
    }
    for (; ed + 7 < end; ed += 8) {
        int r0 = csr[ed     + half];
        int r1 = csr[ed + 2 + half];
        int r2 = csr[ed + 4 + half];
        int r3 = csr[ed + 6 + half];
        EDGE_ADD(r0); EDGE_ADD(r1); EDGE_ADD(r2); EDGE_ADD(r3);
    }
    #pragma unroll
    for (int s = 0; s < 4; ++s) {          // tail: up to 7 edges
        int idx = ed + 2 * s + half;
        if (idx < end) {
            int r = csr[idx];
            EDGE_ADD(r);
        }
    }
    #undef EDGE_ADD

    acc.x += __shfl_xor(acc.x, 32);
    acc.y += __shfl_xor(acc.y, 32);
    acc.z += __shfl_xor(acc.z, 32);
    acc.w += __shfl_xor(acc.w, 32);

    float di = dinv[node];
    uint2 qh = H2[(size_t)node * 32 + sub];
    float2 h01 = __half22float2(*(const __half2*)&qh.x);
    float2 h23 = __half22float2(*(const __half2*)&qh.y);
    float4 bv = ((const float4*)b)[sub];
    float4 o;
    o.x = fmaxf(fmaf(di, acc.x + h01.x, bv.x), 0.f);
    o.y = fmaxf(fmaf(di, acc.y + h01.y, bv.y), 0.f);
    o.z = fmaxf(fmaf(di, acc.z + h23.x, bv.z), 0.f);
    o.w = fmaxf(fmaf(di, acc.w + h23.y, bv.w), 0.f);
    if (half == 0)
        ((float4*)out)[(size_t)node * 32 + sub] = o;
}

// F=16 gather-aggregate from f16 h': 8 lanes/node (4 x uint2, even/odd halves).
__global__ __launch_bounds__(256) void k_agg16(const __half* __restrict__ Ch, const unsigned short* __restrict__ csr,
                                               const int* __restrict__ offs, const float* __restrict__ dinv,
                                               const float* __restrict__ b, float* __restrict__ out, int n) {
    int t = blockIdx.x * 256 + threadIdx.x;
    int node = t >> 3;
    if (node >= n) return;
    int lane = t & 7;
    int sub  = lane & 3;      // uint2 (4 halves) within the 16-f row
    int half = lane >> 2;
    const uint2* C2 = (const uint2*)Ch;   // row stride = 4 uint2
    int ed = offs[node], end = offs[node + 1];
    float4 acc = make_float4(0.f, 0.f, 0.f, 0.f);

    #define EDGE_ADD16(R)                                                        \
        {                                                                        \
            uint2 q = C2[(size_t)(R) * 4 + sub];                                 \
            float2 f01 = __half22float2(*(const __half2*)&q.x);                  \
            float2 f23 = __half22float2(*(const __half2*)&q.y);                  \
            acc.x += f01.x; acc.y += f01.y;                                      \
            acc.z += f23.x; acc.w += f23.y;                                      \
        }

    for (; ed + 3 < end; ed += 4) {
        int r0 = csr[ed     + half];
        int r1 = csr[ed + 2 + half];
        EDGE_ADD16(r0); EDGE_ADD16(r1);
    }
    #pragma unroll
    for (int s = 0; s < 2; ++s) {          // tail: up to 3 edges
        int idx = ed + 2 * s + half;
        if (idx < end) {
            int r = csr[idx];
            EDGE_ADD16(r);
        }
    }
    #undef EDGE_ADD16

    acc.x += __shfl_xor(acc.x, 4);
    acc.y += __shfl_xor(acc.y, 4);
    acc.z += __shfl_xor(acc.z, 4);
    acc.w += __shfl_xor(acc.w, 4);

    float di = dinv[node];
    uint2 qh = C2[(size_t)node * 4 + sub];
    float2 h01 = __half22float2(*(const __half2*)&qh.x);
    float2 h23 = __half22float2(*(const __half2*)&qh.y);
    float4 bv = ((const float4*)b)[sub];
    float4 o;
    o.x = fmaxf(fmaf(di, acc.x + h01.x, bv.x), 0.f);
    o.y = fmaxf(fmaf(di, acc.y + h01.y, bv.y), 0.f);
    o.z = fmaxf(fmaf(di, acc.z + h23.x, bv.z), 0.f);
    o.w = fmaxf(fmaf(di, acc.w + h23.y, bv.w), 0.f);
    if (half == 0)
        ((float4*)out)[(size_t)node * 4 + sub] = o;
}

extern "C" void kernel_launch(void* const* d_in, const int* in_sizes, int n_in,
                              void* d_out, int out_size, void* d_ws, size_t ws_size,
                              hipStream_t stream) {
    const float* x  = (const float*)d_in[0];
    const int*   ei = (const int*)d_in[1];
    const float* W1 = (const float*)d_in[2];
    const float* b1 = (const float*)d_in[3];
    const float* W2 = (const float*)d_in[4];
    const float* b2 = (const float*)d_in[5];
    const float* W3 = (const float*)d_in[6];
    const float* b3 = (const float*)d_in[7];

    const int n = in_sizes[0] / 128;   // 50000 (< 65536, required by 16-bit CSR)
    const int e = in_sizes[1] / 2;
    const int* row = ei;       // source j
    const int* col = ei + e;   // target i

    unsigned short* csr = (unsigned short*)d_ws;
    __half* Ah  = (__half*)(csr + ((e + 1) & ~1));
    float*  B   = (float*)(Ah + (size_t)n * 128);
    __half* Ch  = (__half*)(B + (size_t)n * 128);
    float* dinv = (float*)(Ch + (size_t)n * 16);
    int*   offs = (int*)(dinv + n);
    int*   cnt  = offs + (n + 1);
    int*   cur  = cnt + n;
    int*   bsum = cur + n;
    float* out  = (float*)d_out;

    const int nb = cdiv(n + 1, 256);
    const int e4 = e >> 2;
    const int fillBlocks = 256;          // per replica; grid = 8 * 256

    // --- CSR build ---
    k_zero_int<<<cdiv(n, 256), 256, 0, stream>>>(cnt, n);
    k_count4  <<<cdiv(e4, 256), 256, 0, stream>>>((const int4*)col, cnt, e4, col, e);
    k_scanA   <<<nb, 256, 0, stream>>>(cnt, bsum, dinv, n);
    k_scanC   <<<nb, 256, 0, stream>>>(cnt, bsum, offs, cur, n);
    k_fill_xcd<<<8 * fillBlocks, 256, 0, stream>>>(row, col, cur, csr, e, n, fillBlocks);

    // --- layer 1 ---
    k_gemm128<<<cdiv(n, 128), 256, 0, stream>>>(x, W1, dinv, Ah, n);
    k_agg128 <<<cdiv(n * 64, 256), 256, 0, stream>>>(Ah, csr, offs, dinv, b1, B, n);
    // --- layer 2 ---
    k_gemm128<<<cdiv(n, 128), 256, 0, stream>>>(B, W2, dinv, Ah, n);
    k_agg128 <<<cdiv(n * 64, 256), 256, 0, stream>>>(Ah, csr, offs, dinv, b2, B, n);
    // --- layer 3 ---
    k_gemm16 <<<cdiv(n, 16), 256, 0, stream>>>(B, W3, dinv, Ch, n);
    k_agg16  <<<cdiv(n * 8, 256), 256, 0, stream>>>(Ch, csr, offs, dinv, b3, out, n);
}